// Round 2
// baseline (294.296 us; speedup 1.0000x reference)
//
#include <hip/hip_runtime.h>

#define DIN 128
#define DHID 128
#define DOUT 64

// ---------------- CSR build ----------------

__global__ void k_init(int* counts, int* cursor, int n) {
  int i = blockIdx.x * blockDim.x + threadIdx.x;
  if (i < n) { counts[i] = 0; cursor[i] = 0; }
}

__global__ void k_hist(const int* __restrict__ ei, int E, int* __restrict__ counts) {
  int e = blockIdx.x * blockDim.x + threadIdx.x;
  if (e < E) atomicAdd(&counts[ei[E + e]], 1);
}

__global__ void k_dinv(const int* __restrict__ counts, float* __restrict__ dinv, int n) {
  int i = blockIdx.x * blockDim.x + threadIdx.x;
  if (i < n) dinv[i] = 1.0f / sqrtf((float)(counts[i] + 1));  // +1 self loop
}

__global__ __launch_bounds__(1024) void k_scan1(const int* __restrict__ counts,
                                                int* __restrict__ rowptr,
                                                int* __restrict__ bsums, int n) {
  __shared__ int s[1024];
  int tid = threadIdx.x;
  int idx = blockIdx.x * 1024 + tid;
  int v = (idx < n) ? counts[idx] : 0;
  s[tid] = v;
  __syncthreads();
  for (int off = 1; off < 1024; off <<= 1) {
    int t = (tid >= off) ? s[tid - off] : 0;
    __syncthreads();
    s[tid] += t;
    __syncthreads();
  }
  if (idx < n) rowptr[idx] = s[tid] - v;   // exclusive within block
  if (tid == 1023) bsums[blockIdx.x] = s[1023];
}

__global__ void k_scan2(int* bsums, int nb) {
  int run = 0;
  for (int b = 0; b < nb; ++b) { int v = bsums[b]; bsums[b] = run; run += v; }
}

__global__ __launch_bounds__(1024) void k_scan3(int* __restrict__ rowptr,
                                                const int* __restrict__ bsums, int n, int E) {
  int idx = blockIdx.x * 1024 + threadIdx.x;
  if (idx < n) rowptr[idx] += bsums[blockIdx.x];
  if (idx == 0) rowptr[n] = E;
}

__global__ void k_scatter(const int* __restrict__ ei, int E,
                          const int* __restrict__ rowptr, int* __restrict__ cursor,
                          int* __restrict__ csrc) {
  int e = blockIdx.x * blockDim.x + threadIdx.x;
  if (e >= E) return;
  int s = ei[e];
  int d = ei[E + e];
  int pos = rowptr[d] + atomicAdd(&cursor[d], 1);
  csrc[pos] = s;   // weight dinv[s]*dinv[d] is recomputed on the fly in k_agg
}

// ---------------- tiny weight GEMMs ----------------

template <int NCOL>
__global__ void k_mmnaive(const float* __restrict__ A, const float* __restrict__ B,
                          float* __restrict__ C) {
  int t = blockIdx.x * blockDim.x + threadIdx.x;
  if (t >= 128 * NCOL) return;
  int i = t / NCOL, j = t % NCOL;
  float s = 0.f;
  for (int k = 0; k < 128; ++k) s = fmaf(A[i * 128 + k], B[k * NCOL + j], s);
  C[t] = s;
}

__global__ void k_cvec(const float* __restrict__ b1, const float* __restrict__ b2,
                       const float* __restrict__ b3, const float* __restrict__ W2,
                       const float* __restrict__ W3, float* __restrict__ c1,
                       float* __restrict__ c2, float* __restrict__ c3) {
  __shared__ float t1[DHID];
  int j = threadIdx.x;
  float s = 0.f;
  for (int k = 0; k < DHID; ++k) s = fmaf(b1[k], W2[k * DHID + j], s);
  t1[j] = s;
  __syncthreads();
  if (j < DOUT) {
    float a = 0.f, b = 0.f;
    for (int k = 0; k < DHID; ++k) {
      a = fmaf(t1[k], W3[k * DOUT + j], a);
      b = fmaf(b2[k], W3[k * DOUT + j], b);
    }
    c1[j] = a; c2[j] = b; c3[j] = b3[j];
  }
}

// ---------------- H slice = (X @ Wc)[:, c0:c0+W]  (N x 128 @ 128 x 64, fp32) ----------------

__global__ __launch_bounds__(256) void k_xw(const float* __restrict__ X,
                                            const float* __restrict__ Wc,
                                            float* __restrict__ H, int n,
                                            int c0, int W) {
  // block: 64 rows x 64 cols; K chunked by 64; thread = 4 rows x 4 cols.
  // Only columns [c0, c0+W) are stored, with row stride W (slice buffer).
  __shared__ float Xs[64][68];   // pad -> <=2-way LDS banks
  __shared__ float Ws[64][64];
  int t = threadIdx.x;
  int br = blockIdx.x * 64;
  int r4 = t >> 4, c4 = t & 15;
  float4 acc[4];
#pragma unroll
  for (int i = 0; i < 4; ++i) acc[i] = make_float4(0.f, 0.f, 0.f, 0.f);

  for (int chunk = 0; chunk < 2; ++chunk) {
    int k0 = chunk * 64;
    __syncthreads();
#pragma unroll
    for (int j = 0; j < 4; ++j) {
      int f4 = t + j * 256;          // 0..1023
      int row = f4 >> 4, col4 = f4 & 15;
      int gr = br + row;
      float4 v = make_float4(0.f, 0.f, 0.f, 0.f);
      if (gr < n) v = *(const float4*)&X[(size_t)gr * DIN + k0 + col4 * 4];
      *(float4*)&Xs[row][col4 * 4] = v;
      float4 w = *(const float4*)&Wc[(size_t)(k0 + row) * DOUT + col4 * 4];
      *(float4*)&Ws[row][col4 * 4] = w;
    }
    __syncthreads();
#pragma unroll
    for (int kk = 0; kk < 16; ++kk) {
      float4 xv[4], wv[4];
#pragma unroll
      for (int i = 0; i < 4; ++i) xv[i] = *(const float4*)&Xs[r4 * 4 + i][kk * 4];
#pragma unroll
      for (int q = 0; q < 4; ++q) wv[q] = *(const float4*)&Ws[kk * 4 + q][c4 * 4];
#pragma unroll
      for (int i = 0; i < 4; ++i) {
        acc[i].x = fmaf(xv[i].x, wv[0].x, acc[i].x);
        acc[i].y = fmaf(xv[i].x, wv[0].y, acc[i].y);
        acc[i].z = fmaf(xv[i].x, wv[0].z, acc[i].z);
        acc[i].w = fmaf(xv[i].x, wv[0].w, acc[i].w);
        acc[i].x = fmaf(xv[i].y, wv[1].x, acc[i].x);
        acc[i].y = fmaf(xv[i].y, wv[1].y, acc[i].y);
        acc[i].z = fmaf(xv[i].y, wv[1].z, acc[i].z);
        acc[i].w = fmaf(xv[i].y, wv[1].w, acc[i].w);
        acc[i].x = fmaf(xv[i].z, wv[2].x, acc[i].x);
        acc[i].y = fmaf(xv[i].z, wv[2].y, acc[i].y);
        acc[i].z = fmaf(xv[i].z, wv[2].z, acc[i].z);
        acc[i].w = fmaf(xv[i].z, wv[2].w, acc[i].w);
        acc[i].x = fmaf(xv[i].w, wv[3].x, acc[i].x);
        acc[i].y = fmaf(xv[i].w, wv[3].y, acc[i].y);
        acc[i].z = fmaf(xv[i].w, wv[3].z, acc[i].z);
        acc[i].w = fmaf(xv[i].w, wv[3].w, acc[i].w);
      }
    }
  }
#pragma unroll
  for (int i = 0; i < 4; ++i) {
    int gr = br + r4 * 4 + i;
    int col = c4 * 4;
    if (gr < n && col >= c0 && col < c0 + W)
      *(float4*)&H[(size_t)gr * W + (col - c0)] = acc[i];
  }
}

// ---------------- aggregation: hout = A_hat * hin (+ bias rank-1 terms) ----------------
// Operates on a feature slice of width W (power of two). hin/hout may have
// different row strides (slice buffer stride W vs d_out stride 64).

template <int ROUND>
__global__ __launch_bounds__(256) void k_agg(const float* __restrict__ hin, int hs,
                                             float* __restrict__ hout, int ho,
                                             const int* __restrict__ rowptr,
                                             const int* __restrict__ csrc,
                                             const float* __restrict__ dinv,
                                             float* __restrict__ r1, float* __restrict__ r2,
                                             const float* __restrict__ c1,
                                             const float* __restrict__ c2,
                                             const float* __restrict__ c3,
                                             int n, int W, int wsh, int c0, int pass0) {
  int id = blockIdx.x * blockDim.x + threadIdx.x;
  int node = id >> wsh;
  if (node >= n) return;
  int feat = id & (W - 1);
  int beg = rowptr[node], end = rowptr[node + 1];
  float di = dinv[node];
  float acc = 0.f, racc = 0.f;
  bool doR = (ROUND != 3) && pass0;
  for (int e = beg; e < end; ++e) {
    int s = csrc[e];
    float w = dinv[s] * di;
    acc = fmaf(w, hin[(size_t)s * hs + feat], acc);
    if (doR) {
      if (ROUND == 1) racc += w;
      if (ROUND == 2) racc = fmaf(w, r1[s], racc);
    }
  }
  float d2 = di * di;                          // self-loop weight
  acc = fmaf(d2, hin[(size_t)node * hs + feat], acc);
  if (ROUND == 1 && doR) { racc += d2; if (feat == 0) r1[node] = racc; }
  if (ROUND == 2 && doR) { racc = fmaf(d2, r1[node], racc); if (feat == 0) r2[node] = racc; }
  if (ROUND == 3) {
    int cf = c0 + feat;
    acc = fmaf(r2[node], c1[cf], acc);
    acc = fmaf(r1[node], c2[cf], acc);
    acc += c3[cf];
  }
  hout[(size_t)node * ho + feat] = acc;
}

// ---------------- launch ----------------

extern "C" void kernel_launch(void* const* d_in, const int* in_sizes, int n_in,
                              void* d_out, int out_size, void* d_ws, size_t ws_size,
                              hipStream_t stream) {
  const float* X  = (const float*)d_in[0];
  const int*   ei = (const int*)d_in[1];
  const float* W1 = (const float*)d_in[2];
  const float* b1 = (const float*)d_in[3];
  const float* W2 = (const float*)d_in[4];
  const float* b2 = (const float*)d_in[5];
  const float* W3 = (const float*)d_in[6];
  const float* b3 = (const float*)d_in[7];
  const int N = in_sizes[0] / DIN;
  const int E = in_sizes[1] / 2;
  float* out = (float*)d_out;

  auto AL = [](size_t x) -> size_t { return (x + 255) & ~(size_t)255; };

  // fixed footprint (counts aliases r1, cursor aliases r2: CSR build fully
  // precedes any aggregation, so lifetimes are disjoint)
  size_t fixedBytes = AL((size_t)(N + 1) * 4)   // rowptr
                    + AL(256 * 4)               // bsums
                    + AL((size_t)N * 4)         // dinv
                    + AL((size_t)E * 4)         // csrc
                    + AL((size_t)N * 4)         // r1 / counts
                    + AL((size_t)N * 4)         // r2 / cursor
                    + AL((size_t)DIN * DHID * 4)// wtmp
                    + AL((size_t)DIN * DOUT * 4)// wc
                    + 3 * AL(DOUT * 4);         // c1..c3
  // choose feature-slice passes so we NEVER exceed ws_size
  int npass = 1;
  while (npass < 8 && fixedBytes + AL((size_t)N * (DOUT / npass) * 4) > ws_size)
    npass <<= 1;
  const int W = DOUT / npass;
  int wsh = 0; while ((1 << wsh) < W) ++wsh;

  char* p = (char*)d_ws;
  auto alloc = [&](size_t nbytes) -> void* {
    void* r = (void*)p;
    p += AL(nbytes);
    return r;
  };
  int*   rowptr = (int*)alloc((size_t)(N + 1) * 4);
  int*   bsums  = (int*)alloc(256 * 4);
  float* dinv   = (float*)alloc((size_t)N * 4);
  int*   csrc   = (int*)alloc((size_t)E * 4);
  int*   counts = (int*)alloc((size_t)N * 4);   // aliased: becomes r1
  int*   cursor = (int*)alloc((size_t)N * 4);   // aliased: becomes r2
  float* wtmp   = (float*)alloc((size_t)DIN * DHID * 4);
  float* wc     = (float*)alloc((size_t)DIN * DOUT * 4);
  float* c1     = (float*)alloc(DOUT * 4);
  float* c2     = (float*)alloc(DOUT * 4);
  float* c3     = (float*)alloc(DOUT * 4);
  float* Hws    = (float*)alloc((size_t)N * W * 4);
  float* r1     = (float*)counts;
  float* r2     = (float*)cursor;

  // ---- CSR build (once) ----
  k_init<<<(N + 255) / 256, 256, 0, stream>>>(counts, cursor, N);
  k_hist<<<(E + 255) / 256, 256, 0, stream>>>(ei, E, counts);
  k_dinv<<<(N + 255) / 256, 256, 0, stream>>>(counts, dinv, N);
  int nb = (N + 1023) / 1024;
  k_scan1<<<nb, 1024, 0, stream>>>(counts, rowptr, bsums, N);
  k_scan2<<<1, 1, 0, stream>>>(bsums, nb);
  k_scan3<<<nb, 1024, 0, stream>>>(rowptr, bsums, N, E);
  k_scatter<<<(E + 255) / 256, 256, 0, stream>>>(ei, E, rowptr, cursor, csrc);

  // ---- fused weights (once) ----
  k_mmnaive<128><<<(128 * 128 + 255) / 256, 256, 0, stream>>>(W1, W2, wtmp);
  k_mmnaive<64><<<(128 * 64 + 255) / 256, 256, 0, stream>>>(wtmp, W3, wc);
  k_cvec<<<1, 128, 0, stream>>>(b1, b2, b3, W2, W3, c1, c2, c3);

  // ---- per feature-slice pass: GEMM slice + 3 aggregation rounds ----
  for (int pp = 0; pp < npass; ++pp) {
    int c0 = pp * W;
    int pass0 = (pp == 0) ? 1 : 0;
    k_xw<<<(N + 63) / 64, 256, 0, stream>>>(X, wc, Hws, N, c0, W);
    int gb = (int)(((size_t)N * W + 255) / 256);
    k_agg<1><<<gb, 256, 0, stream>>>(Hws, W, out + c0, DOUT, rowptr, csrc, dinv,
                                     r1, r2, c1, c2, c3, N, W, wsh, c0, pass0);
    k_agg<2><<<gb, 256, 0, stream>>>(out + c0, DOUT, Hws, W, rowptr, csrc, dinv,
                                     r1, r2, c1, c2, c3, N, W, wsh, c0, pass0);
    k_agg<3><<<gb, 256, 0, stream>>>(Hws, W, out + c0, DOUT, rowptr, csrc, dinv,
                                     r1, r2, c1, c2, c3, N, W, wsh, c0, 0);
  }
}

// Round 4
// 200.569 us; speedup vs baseline: 1.4673x; 1.4673x over previous
//
#include <hip/hip_runtime.h>

#define DIN 128
#define DHID 128
#define DOUT 64

__device__ __forceinline__ float bf2f(ushort u) {
  return __uint_as_float(((unsigned)u) << 16);
}
__device__ __forceinline__ ushort f2bf(float f) {  // round-to-nearest-even
  unsigned u = __float_as_uint(f);
  return (ushort)((u + 0x7fffu + ((u >> 16) & 1u)) >> 16);
}

// ---------------- CSR build ----------------

__global__ void k_init(int* counts, int* cursor, int n) {
  int i = blockIdx.x * blockDim.x + threadIdx.x;
  if (i < n) { counts[i] = 0; cursor[i] = 0; }
}

__global__ void k_hist(const int* __restrict__ ei, int E, int* __restrict__ counts) {
  int e = blockIdx.x * blockDim.x + threadIdx.x;
  if (e < E) atomicAdd(&counts[ei[E + e]], 1);
}

__global__ void k_dinv(const int* __restrict__ counts, float* __restrict__ dinv, int n) {
  int i = blockIdx.x * blockDim.x + threadIdx.x;
  if (i < n) dinv[i] = 1.0f / sqrtf((float)(counts[i] + 1));  // +1 self loop
}

__global__ __launch_bounds__(1024) void k_scan1(const int* __restrict__ counts,
                                                int* __restrict__ rowptr,
                                                int* __restrict__ bsums, int n) {
  __shared__ int s[1024];
  int tid = threadIdx.x;
  int idx = blockIdx.x * 1024 + tid;
  int v = (idx < n) ? counts[idx] : 0;
  s[tid] = v;
  __syncthreads();
  for (int off = 1; off < 1024; off <<= 1) {
    int t = (tid >= off) ? s[tid - off] : 0;
    __syncthreads();
    s[tid] += t;
    __syncthreads();
  }
  if (idx < n) rowptr[idx] = s[tid] - v;   // exclusive within block
  if (tid == 1023) bsums[blockIdx.x] = s[1023];
}

__global__ void k_scan2(int* bsums, int nb) {
  // one wave, nb <= 64 (N <= 65536). exclusive scan of block sums.
  int l = threadIdx.x;
  if (nb <= 64) {
    int v = (l < nb) ? bsums[l] : 0;
    int orig = v;
    for (int off = 1; off < 64; off <<= 1) {
      int t = __shfl_up(v, off);
      if (l >= off) v += t;
    }
    if (l < nb) bsums[l] = v - orig;
  } else if (l == 0) {
    int run = 0;
    for (int b = 0; b < nb; ++b) { int v = bsums[b]; bsums[b] = run; run += v; }
  }
}

__global__ __launch_bounds__(1024) void k_scan3(int* __restrict__ rowptr,
                                                const int* __restrict__ bsums, int n, int E) {
  int idx = blockIdx.x * 1024 + threadIdx.x;
  if (idx < n) rowptr[idx] += bsums[blockIdx.x];
  if (idx == 0) rowptr[n] = E;
}

__global__ void k_scatter(const int* __restrict__ ei, int E,
                          const int* __restrict__ rowptr, int* __restrict__ cursor,
                          int* __restrict__ csrc) {
  int e = blockIdx.x * blockDim.x + threadIdx.x;
  if (e >= E) return;
  int s = ei[e];
  int d = ei[E + e];
  int pos = rowptr[d] + atomicAdd(&cursor[d], 1);
  csrc[pos] = s;   // weight dinv[s]*dinv[d] recomputed on the fly
}

// ---------------- tiny weight GEMMs ----------------

template <int NCOL>
__global__ void k_mmnaive(const float* __restrict__ A, const float* __restrict__ B,
                          float* __restrict__ C) {
  int t = blockIdx.x * blockDim.x + threadIdx.x;
  if (t >= 128 * NCOL) return;
  int i = t / NCOL, j = t % NCOL;
  float s = 0.f;
  for (int k = 0; k < 128; ++k) s = fmaf(A[i * 128 + k], B[k * NCOL + j], s);
  C[t] = s;
}

__global__ void k_cvec(const float* __restrict__ b1, const float* __restrict__ b2,
                       const float* __restrict__ b3, const float* __restrict__ W2,
                       const float* __restrict__ W3, float* __restrict__ c1,
                       float* __restrict__ c2, float* __restrict__ c3) {
  __shared__ float t1[DHID];
  int j = threadIdx.x;
  float s = 0.f;
  for (int k = 0; k < DHID; ++k) s = fmaf(b1[k], W2[k * DHID + j], s);
  t1[j] = s;
  __syncthreads();
  if (j < DOUT) {
    float a = 0.f, b = 0.f;
    for (int k = 0; k < DHID; ++k) {
      a = fmaf(t1[k], W3[k * DOUT + j], a);
      b = fmaf(b2[k], W3[k * DOUT + j], b);
    }
    c1[j] = a; c2[j] = b; c3[j] = b3[j];
  }
}

// ---------------- H slice = (X @ Wc)[:, c0:c0+W]  -> bf16 ----------------

__global__ __launch_bounds__(256) void k_xw(const float* __restrict__ X,
                                            const float* __restrict__ Wc,
                                            ushort* __restrict__ H, int n,
                                            int c0, int W) {
  __shared__ float Xs[64][68];
  __shared__ float Ws[64][64];
  int t = threadIdx.x;
  int br = blockIdx.x * 64;
  int r4 = t >> 4, c4 = t & 15;
  float4 acc[4];
#pragma unroll
  for (int i = 0; i < 4; ++i) acc[i] = make_float4(0.f, 0.f, 0.f, 0.f);

  for (int chunk = 0; chunk < 2; ++chunk) {
    int k0 = chunk * 64;
    __syncthreads();
#pragma unroll
    for (int j = 0; j < 4; ++j) {
      int f4 = t + j * 256;
      int row = f4 >> 4, col4 = f4 & 15;
      int gr = br + row;
      float4 v = make_float4(0.f, 0.f, 0.f, 0.f);
      if (gr < n) v = *(const float4*)&X[(size_t)gr * DIN + k0 + col4 * 4];
      *(float4*)&Xs[row][col4 * 4] = v;
      float4 w = *(const float4*)&Wc[(size_t)(k0 + row) * DOUT + col4 * 4];
      *(float4*)&Ws[row][col4 * 4] = w;
    }
    __syncthreads();
#pragma unroll
    for (int kk = 0; kk < 16; ++kk) {
      float4 xv[4], wv[4];
#pragma unroll
      for (int i = 0; i < 4; ++i) xv[i] = *(const float4*)&Xs[r4 * 4 + i][kk * 4];
#pragma unroll
      for (int q = 0; q < 4; ++q) wv[q] = *(const float4*)&Ws[kk * 4 + q][c4 * 4];
#pragma unroll
      for (int i = 0; i < 4; ++i) {
        acc[i].x = fmaf(xv[i].x, wv[0].x, acc[i].x);
        acc[i].y = fmaf(xv[i].x, wv[0].y, acc[i].y);
        acc[i].z = fmaf(xv[i].x, wv[0].z, acc[i].z);
        acc[i].w = fmaf(xv[i].x, wv[0].w, acc[i].w);
        acc[i].x = fmaf(xv[i].y, wv[1].x, acc[i].x);
        acc[i].y = fmaf(xv[i].y, wv[1].y, acc[i].y);
        acc[i].z = fmaf(xv[i].y, wv[1].z, acc[i].z);
        acc[i].w = fmaf(xv[i].y, wv[1].w, acc[i].w);
        acc[i].x = fmaf(xv[i].z, wv[2].x, acc[i].x);
        acc[i].y = fmaf(xv[i].z, wv[2].y, acc[i].y);
        acc[i].z = fmaf(xv[i].z, wv[2].z, acc[i].z);
        acc[i].w = fmaf(xv[i].z, wv[2].w, acc[i].w);
        acc[i].x = fmaf(xv[i].w, wv[3].x, acc[i].x);
        acc[i].y = fmaf(xv[i].w, wv[3].y, acc[i].y);
        acc[i].z = fmaf(xv[i].w, wv[3].z, acc[i].z);
        acc[i].w = fmaf(xv[i].w, wv[3].w, acc[i].w);
      }
    }
  }
#pragma unroll
  for (int i = 0; i < 4; ++i) {
    int gr = br + r4 * 4 + i;
    int col = c4 * 4;
    if (gr < n && col >= c0 && col < c0 + W) {
      ushort4 hv;
      hv.x = f2bf(acc[i].x); hv.y = f2bf(acc[i].y);
      hv.z = f2bf(acc[i].z); hv.w = f2bf(acc[i].w);
      *(ushort4*)&H[(size_t)gr * W + (col - c0)] = hv;
    }
  }
}

// ---------------- aggregation: hout = A_hat * hin (+ rank-1 bias terms) ----------------
// bf16 in; bf16 out (rounds 1,2) or fp32 out (round 3). fp32 accumulate.

template <int ROUND>
__global__ __launch_bounds__(256) void k_agg(const ushort* __restrict__ hin, int hs,
                                             ushort* __restrict__ ho16,
                                             float* __restrict__ ho32, int ho,
                                             const int* __restrict__ rowptr,
                                             const int* __restrict__ csrc,
                                             const float* __restrict__ dinv,
                                             float* __restrict__ r1, float* __restrict__ r2,
                                             const float* __restrict__ c1,
                                             const float* __restrict__ c2,
                                             const float* __restrict__ c3,
                                             int n, int W, int wsh, int c0, int pass0) {
  int id = blockIdx.x * blockDim.x + threadIdx.x;
  int node = id >> wsh;
  if (node >= n) return;
  int feat = id & (W - 1);
  int beg = rowptr[node], end = rowptr[node + 1];
  float di = dinv[node];
  float a0 = 0.f, a1 = 0.f, a2 = 0.f, a3 = 0.f, racc = 0.f;
  bool doR = (ROUND != 3) && pass0;
  int e = beg;
  for (; e + 4 <= end; e += 4) {          // 4 independent gathers in flight
    int s0 = csrc[e], s1 = csrc[e + 1], s2 = csrc[e + 2], s3 = csrc[e + 3];
    float w0 = dinv[s0] * di, w1 = dinv[s1] * di;
    float w2 = dinv[s2] * di, w3 = dinv[s3] * di;
    float h0 = bf2f(hin[(size_t)s0 * hs + feat]);
    float h1 = bf2f(hin[(size_t)s1 * hs + feat]);
    float h2 = bf2f(hin[(size_t)s2 * hs + feat]);
    float h3 = bf2f(hin[(size_t)s3 * hs + feat]);
    a0 = fmaf(w0, h0, a0); a1 = fmaf(w1, h1, a1);
    a2 = fmaf(w2, h2, a2); a3 = fmaf(w3, h3, a3);
    if (doR) {
      if (ROUND == 1) racc += (w0 + w1) + (w2 + w3);
      if (ROUND == 2) {
        racc = fmaf(w0, r1[s0], racc); racc = fmaf(w1, r1[s1], racc);
        racc = fmaf(w2, r1[s2], racc); racc = fmaf(w3, r1[s3], racc);
      }
    }
  }
  for (; e < end; ++e) {
    int s = csrc[e];
    float w = dinv[s] * di;
    a0 = fmaf(w, bf2f(hin[(size_t)s * hs + feat]), a0);
    if (doR) {
      if (ROUND == 1) racc += w;
      if (ROUND == 2) racc = fmaf(w, r1[s], racc);
    }
  }
  float acc = (a0 + a1) + (a2 + a3);
  float d2 = di * di;                      // self-loop weight
  acc = fmaf(d2, bf2f(hin[(size_t)node * hs + feat]), acc);
  if (ROUND == 1 && doR) { racc += d2; if (feat == 0) r1[node] = racc; }
  if (ROUND == 2 && doR) { racc = fmaf(d2, r1[node], racc); if (feat == 0) r2[node] = racc; }
  if (ROUND == 3) {
    int cf = c0 + feat;
    acc = fmaf(r2[node], c1[cf], acc);
    acc = fmaf(r1[node], c2[cf], acc);
    acc += c3[cf];
    ho32[(size_t)node * ho + feat] = acc;
  } else {
    ho16[(size_t)node * hs + feat] = f2bf(acc);
  }
}

// ---------------- launch ----------------

extern "C" void kernel_launch(void* const* d_in, const int* in_sizes, int n_in,
                              void* d_out, int out_size, void* d_ws, size_t ws_size,
                              hipStream_t stream) {
  const float* X  = (const float*)d_in[0];
  const int*   ei = (const int*)d_in[1];
  const float* W1 = (const float*)d_in[2];
  const float* b1 = (const float*)d_in[3];
  const float* W2 = (const float*)d_in[4];
  const float* b2 = (const float*)d_in[5];
  const float* W3 = (const float*)d_in[6];
  const float* b3 = (const float*)d_in[7];
  const int N = in_sizes[0] / DIN;
  const int E = in_sizes[1] / 2;
  float* out = (float*)d_out;

  auto AL = [](size_t x) -> size_t { return (x + 255) & ~(size_t)255; };

  size_t fixedBytes = AL((size_t)(N + 1) * 4)    // rowptr
                    + AL(256 * 4)                // bsums
                    + AL((size_t)N * 4)          // dinv
                    + AL((size_t)E * 4)          // csrc
                    + AL((size_t)N * 4)          // r1 / counts
                    + AL((size_t)N * 4)          // r2 / cursor
                    + AL((size_t)DIN * DHID * 4) // wtmp
                    + AL((size_t)DIN * DOUT * 4) // wc
                    + 3 * AL(DOUT * 4);          // c1..c3
  // two bf16 ping-pong slice buffers; pick npass so we never exceed ws_size
  int npass = 1;
  while (npass < 8 && fixedBytes + 2 * AL((size_t)N * (DOUT / npass) * 2) > ws_size)
    npass <<= 1;
  const int W = DOUT / npass;
  int wsh = 0; while ((1 << wsh) < W) ++wsh;

  char* p = (char*)d_ws;
  auto alloc = [&](size_t nbytes) -> void* {
    void* r = (void*)p;
    p += AL(nbytes);
    return r;
  };
  int*    rowptr = (int*)alloc((size_t)(N + 1) * 4);
  int*    bsums  = (int*)alloc(256 * 4);
  float*  dinv   = (float*)alloc((size_t)N * 4);
  int*    csrc   = (int*)alloc((size_t)E * 4);
  int*    counts = (int*)alloc((size_t)N * 4);   // aliased -> r1
  int*    cursor = (int*)alloc((size_t)N * 4);   // aliased -> r2
  float*  wtmp   = (float*)alloc((size_t)DIN * DHID * 4);
  float*  wc     = (float*)alloc((size_t)DIN * DOUT * 4);
  float*  c1     = (float*)alloc(DOUT * 4);
  float*  c2     = (float*)alloc(DOUT * 4);
  float*  c3     = (float*)alloc(DOUT * 4);
  ushort* H1     = (ushort*)alloc((size_t)N * W * 2);
  ushort* H2     = (ushort*)alloc((size_t)N * W * 2);
  float*  r1     = (float*)counts;
  float*  r2     = (float*)cursor;

  // ---- CSR build (once) ----
  k_init<<<(N + 255) / 256, 256, 0, stream>>>(counts, cursor, N);
  k_hist<<<(E + 255) / 256, 256, 0, stream>>>(ei, E, counts);
  k_dinv<<<(N + 255) / 256, 256, 0, stream>>>(counts, dinv, N);
  int nb = (N + 1023) / 1024;
  k_scan1<<<nb, 1024, 0, stream>>>(counts, rowptr, bsums, N);
  k_scan2<<<1, 64, 0, stream>>>(bsums, nb);
  k_scan3<<<nb, 1024, 0, stream>>>(rowptr, bsums, N, E);
  k_scatter<<<(E + 255) / 256, 256, 0, stream>>>(ei, E, rowptr, cursor, csrc);

  // ---- fused weights (once) ----
  k_mmnaive<128><<<(128 * 128 + 255) / 256, 256, 0, stream>>>(W1, W2, wtmp);
  k_mmnaive<64><<<(128 * 64 + 255) / 256, 256, 0, stream>>>(wtmp, W3, wc);
  k_cvec<<<1, 128, 0, stream>>>(b1, b2, b3, W2, W3, c1, c2, c3);

  // ---- per feature-slice pass: GEMM slice + 3 aggregation rounds ----
  for (int pp = 0; pp < npass; ++pp) {
    int c0 = pp * W;
    int pass0 = (pp == 0) ? 1 : 0;
    k_xw<<<(N + 63) / 64, 256, 0, stream>>>(X, wc, H1, N, c0, W);
    int gb = (int)(((size_t)N * W + 255) / 256);
    k_agg<1><<<gb, 256, 0, stream>>>(H1, W, H2, nullptr, DOUT, rowptr, csrc, dinv,
                                     r1, r2, c1, c2, c3, N, W, wsh, c0, pass0);
    k_agg<2><<<gb, 256, 0, stream>>>(H2, W, H1, nullptr, DOUT, rowptr, csrc, dinv,
                                     r1, r2, c1, c2, c3, N, W, wsh, c0, pass0);
    k_agg<3><<<gb, 256, 0, stream>>>(H1, W, nullptr, out + c0, DOUT, rowptr, csrc, dinv,
                                     r1, r2, c1, c2, c3, N, W, wsh, c0, 0);
  }
}